// Round 1
// baseline (171.400 us; speedup 1.0000x reference)
//
#include <hip/hip_runtime.h>
#include <hip/hip_bf16.h>

typedef __attribute__((ext_vector_type(8))) short short8;
typedef __attribute__((ext_vector_type(4))) float f32x4;

#define BHN 32
#define LL 2048
#define DD 128
#define SCALE 0.08838834764831845f

__device__ __forceinline__ unsigned short f2bf(float f) {
  unsigned int u = __float_as_uint(f);
  u = u + 0x7FFFu + ((u >> 16) & 1u);   // RNE; inputs are finite gaussians
  return (unsigned short)(u >> 16);
}
__device__ __forceinline__ unsigned int pk2(float a, float b) {
  return (unsigned int)f2bf(a) | ((unsigned int)f2bf(b) << 16);
}

// ---------------------------------------------------------------------------
// Kernel 1: W[bh][d2][d1] += sum_m V[bh][m][d2] * K[bh][m][d1]
// grid = 32 heads * 16 m-chunks (128 rows each), block = 256 (4 waves)
// ---------------------------------------------------------------------------
__global__ __launch_bounds__(256) void ktv_kernel(const float* __restrict__ Kg,
                                                  const float* __restrict__ Vg,
                                                  float* __restrict__ W) {
  const int bh = blockIdx.x >> 4;
  const int chunk = blockIdx.x & 15;
  const int t = threadIdx.x;

  // transposed bf16 tiles: [d][m], m-tile = 32, stride 40 (80B rows, 16B-aligned)
  __shared__ unsigned short Kt[128][40];
  __shared__ unsigned short Vt[128][40];

  const int wave = t >> 6;
  const int lane = t & 63;
  const int lr = lane & 15;   // frag row/col
  const int kg = lane >> 4;   // k-group (8 contiguous k per lane)

  f32x4 acc[2][8];
#pragma unroll
  for (int a = 0; a < 2; ++a)
#pragma unroll
    for (int b = 0; b < 8; ++b) acc[a][b] = (f32x4)(0.0f);

  const int dq = t >> 3;        // 0..31 : d-quad
  const int mr = (t & 7) << 2;  // 0..28 : m row base (4 rows per thread)
  const size_t hb = (size_t)bh * LL * DD;

  for (int tile = 0; tile < 4; ++tile) {
    const int m0 = chunk * 128 + tile * 32;
    const float* kp = Kg + hb + (size_t)(m0 + mr) * DD + dq * 4;
    const float* vp = Vg + hb + (size_t)(m0 + mr) * DD + dq * 4;
    float4 k0 = *(const float4*)(kp);
    float4 k1 = *(const float4*)(kp + DD);
    float4 k2 = *(const float4*)(kp + 2 * DD);
    float4 k3 = *(const float4*)(kp + 3 * DD);
    float4 v0 = *(const float4*)(vp);
    float4 v1 = *(const float4*)(vp + DD);
    float4 v2 = *(const float4*)(vp + 2 * DD);
    float4 v3 = *(const float4*)(vp + 3 * DD);

    if (tile) __syncthreads();  // previous tile's frag reads done

    // transpose-write: pack (m, m+1) pairs per d
    *(unsigned int*)&Kt[dq * 4 + 0][mr]     = pk2(k0.x, k1.x);
    *(unsigned int*)&Kt[dq * 4 + 0][mr + 2] = pk2(k2.x, k3.x);
    *(unsigned int*)&Kt[dq * 4 + 1][mr]     = pk2(k0.y, k1.y);
    *(unsigned int*)&Kt[dq * 4 + 1][mr + 2] = pk2(k2.y, k3.y);
    *(unsigned int*)&Kt[dq * 4 + 2][mr]     = pk2(k0.z, k1.z);
    *(unsigned int*)&Kt[dq * 4 + 2][mr + 2] = pk2(k2.z, k3.z);
    *(unsigned int*)&Kt[dq * 4 + 3][mr]     = pk2(k0.w, k1.w);
    *(unsigned int*)&Kt[dq * 4 + 3][mr + 2] = pk2(k2.w, k3.w);

    *(unsigned int*)&Vt[dq * 4 + 0][mr]     = pk2(v0.x, v1.x);
    *(unsigned int*)&Vt[dq * 4 + 0][mr + 2] = pk2(v2.x, v3.x);
    *(unsigned int*)&Vt[dq * 4 + 1][mr]     = pk2(v0.y, v1.y);
    *(unsigned int*)&Vt[dq * 4 + 1][mr + 2] = pk2(v2.y, v3.y);
    *(unsigned int*)&Vt[dq * 4 + 2][mr]     = pk2(v0.z, v1.z);
    *(unsigned int*)&Vt[dq * 4 + 2][mr + 2] = pk2(v2.z, v3.z);
    *(unsigned int*)&Vt[dq * 4 + 3][mr]     = pk2(v0.w, v1.w);
    *(unsigned int*)&Vt[dq * 4 + 3][mr + 2] = pk2(v2.w, v3.w);

    __syncthreads();

    // A = V^T tile rows (d2), B = K^T tile cols (d1); contraction k = m (32)
    short8 a0 = *(const short8*)&Vt[wave * 32 + lr][kg * 8];
    short8 a1 = *(const short8*)&Vt[wave * 32 + 16 + lr][kg * 8];
#pragma unroll
    for (int tc = 0; tc < 8; ++tc) {
      short8 b = *(const short8*)&Kt[tc * 16 + lr][kg * 8];
      acc[0][tc] = __builtin_amdgcn_mfma_f32_16x16x32_bf16(a0, b, acc[0][tc], 0, 0, 0);
      acc[1][tc] = __builtin_amdgcn_mfma_f32_16x16x32_bf16(a1, b, acc[1][tc], 0, 0, 0);
    }
  }

  // epilogue: fp32 atomic partial-sum into W[bh][d2][d1]
  float* Wh = W + (size_t)bh * DD * DD;
#pragma unroll
  for (int tr = 0; tr < 2; ++tr)
#pragma unroll
    for (int tc = 0; tc < 8; ++tc)
#pragma unroll
      for (int r = 0; r < 4; ++r) {
        int i = wave * 32 + tr * 16 + kg * 4 + r;  // d2 (C/D row)
        int j = tc * 16 + lr;                      // d1 (C/D col)
        atomicAdd(&Wh[i * DD + j], acc[tr][tc][r]);
      }
}

// ---------------------------------------------------------------------------
// Kernel 2: O[bh][l][d2] = SCALE * sum_d1 Q[bh][l][d1] * W[bh][d2][d1]
// grid = 32 heads * 16 row-blocks (128 rows each), block = 256 (4 waves)
// ---------------------------------------------------------------------------
__global__ __launch_bounds__(256) void qw_kernel(const float* __restrict__ Qg,
                                                 const float* __restrict__ W,
                                                 float* __restrict__ Og) {
  const int bh = blockIdx.x >> 4;
  const int rblk = blockIdx.x & 15;
  const int t = threadIdx.x;

  __shared__ unsigned short Ws[128][136];  // [d2][d1] bf16, pad 8 (272B rows)

  const float* Wh = W + (size_t)bh * DD * DD;
#pragma unroll
  for (int it = 0; it < 16; ++it) {
    int f = t + it * 256;  // float4 index
    int row = f >> 5;
    int c4 = f & 31;
    float4 w4 = *(const float4*)(Wh + (size_t)f * 4);
    uint2 pkv;
    pkv.x = pk2(w4.x, w4.y);
    pkv.y = pk2(w4.z, w4.w);
    *(uint2*)&Ws[row][c4 * 4] = pkv;
  }
  __syncthreads();

  const int wave = t >> 6;
  const int lane = t & 63;
  const int lr = lane & 15;
  const int kg = lane >> 4;

  f32x4 acc[2][8];
#pragma unroll
  for (int a = 0; a < 2; ++a)
#pragma unroll
    for (int b = 0; b < 8; ++b) acc[a][b] = (f32x4)(0.0f);

  const float* Qb = Qg + ((size_t)bh * LL + rblk * 128) * DD;

#pragma unroll
  for (int ks = 0; ks < 4; ++ks) {
    short8 bfr[8];
#pragma unroll
    for (int tc = 0; tc < 8; ++tc)
      bfr[tc] = *(const short8*)&Ws[tc * 16 + lr][ks * 32 + kg * 8];
#pragma unroll
    for (int tr = 0; tr < 2; ++tr) {
      const float* qp = Qb + (size_t)(wave * 32 + tr * 16 + lr) * DD + ks * 32 + kg * 8;
      float4 q0 = *(const float4*)qp;
      float4 q1 = *(const float4*)(qp + 4);
      short8 af;
      af[0] = (short)f2bf(q0.x);
      af[1] = (short)f2bf(q0.y);
      af[2] = (short)f2bf(q0.z);
      af[3] = (short)f2bf(q0.w);
      af[4] = (short)f2bf(q1.x);
      af[5] = (short)f2bf(q1.y);
      af[6] = (short)f2bf(q1.z);
      af[7] = (short)f2bf(q1.w);
#pragma unroll
      for (int tc = 0; tc < 8; ++tc)
        acc[tr][tc] = __builtin_amdgcn_mfma_f32_16x16x32_bf16(af, bfr[tc], acc[tr][tc], 0, 0, 0);
    }
  }

  float* Ob = Og + ((size_t)bh * LL + rblk * 128) * DD;
#pragma unroll
  for (int tr = 0; tr < 2; ++tr)
#pragma unroll
    for (int tc = 0; tc < 8; ++tc)
#pragma unroll
      for (int r = 0; r < 4; ++r) {
        int row = wave * 32 + tr * 16 + kg * 4 + r;
        int col = tc * 16 + lr;
        Ob[(size_t)row * DD + col] = acc[tr][tc][r] * SCALE;
      }
}

extern "C" void kernel_launch(void* const* d_in, const int* in_sizes, int n_in,
                              void* d_out, int out_size, void* d_ws, size_t ws_size,
                              hipStream_t stream) {
  const float* Q = (const float*)d_in[0];
  const float* K = (const float*)d_in[1];
  const float* V = (const float*)d_in[2];
  float* W = (float*)d_ws;   // 32*128*128 fp32 = 2 MB
  float* O = (float*)d_out;

  hipMemsetAsync(d_ws, 0, (size_t)BHN * DD * DD * sizeof(float), stream);
  ktv_kernel<<<dim3(512), dim3(256), 0, stream>>>(K, V, W);
  qw_kernel<<<dim3(512), dim3(256), 0, stream>>>(Q, W, O);
}

// Round 3
// 147.983 us; speedup vs baseline: 1.1582x; 1.1582x over previous
//
#include <hip/hip_runtime.h>
#include <hip/hip_bf16.h>

typedef __attribute__((ext_vector_type(8))) short short8;
typedef __attribute__((ext_vector_type(4))) float f32x4;

#define LL 2048
#define DD 128
#define NH 32                      // B*H heads
#define SCALE 0.08838834764831845f // 1/sqrt(128)

__device__ __forceinline__ unsigned short f2bf(float f) {
  unsigned int u = __float_as_uint(f);
  u = u + 0x7FFFu + ((u >> 16) & 1u);  // RNE; inputs finite
  return (unsigned short)(u >> 16);
}
__device__ __forceinline__ unsigned int pk2(float a, float b) {
  return (unsigned int)f2bf(a) | ((unsigned int)f2bf(b) << 16);
}
__device__ __forceinline__ float fc(const float4& v, int c) {
  return ((const float*)&v)[c];
}

// ---------------------------------------------------------------------------
// Kernel 1: per-chunk partial W_p[d2][d1] = sum_{m in chunk} V[m][d2]*K[m][d1]
// grid = 32 heads * 16 chunks (128 m-rows each), block = 256 (4 waves).
// PARTIAL: store 64KB partial to P + bid*16384. else: HW fp32 atomic into W.
// Register double-buffer: prefetch tile t+1 while transposing/MFMAing tile t.
// ---------------------------------------------------------------------------
template <bool PARTIAL>
__global__ __launch_bounds__(256) void ktv_kernel(const float* __restrict__ Kg,
                                                  const float* __restrict__ Vg,
                                                  float* __restrict__ P) {
  const int bh = blockIdx.x >> 4;
  const int chunk = blockIdx.x & 15;
  const int t = threadIdx.x;

  __shared__ unsigned short Kt[128][40];  // [d][m-tile], 80B rows, 16B aligned
  __shared__ unsigned short Vt[128][40];

  const int wave = t >> 6;
  const int lane = t & 63;
  const int lr = lane & 15;
  const int kg = lane >> 4;

  f32x4 acc[2][8];
#pragma unroll
  for (int a = 0; a < 2; ++a)
#pragma unroll
    for (int b = 0; b < 8; ++b) acc[a][b] = (f32x4)(0.0f);

  const int dq = t >> 3;        // 0..31 d-quad
  const int mr = (t & 7) << 2;  // 0..28 m-row base (4 rows/thread)
  const size_t hb = (size_t)bh * LL * DD;
  const float* kbase = Kg + hb + (size_t)(chunk * 128 + mr) * DD + dq * 4;
  const float* vbase = Vg + hb + (size_t)(chunk * 128 + mr) * DD + dq * 4;

  float4 ka[4], va[4], kb[4], vb[4];
#pragma unroll
  for (int r = 0; r < 4; ++r) {
    ka[r] = *(const float4*)(kbase + r * DD);
    va[r] = *(const float4*)(vbase + r * DD);
  }

#pragma unroll
  for (int tile = 0; tile < 4; ++tile) {
    if (tile < 3) {  // prefetch next tile into regs (stays in flight across MFMA)
      const float* kp = kbase + (size_t)(tile + 1) * 32 * DD;
      const float* vp = vbase + (size_t)(tile + 1) * 32 * DD;
#pragma unroll
      for (int r = 0; r < 4; ++r) {
        kb[r] = *(const float4*)(kp + r * DD);
        vb[r] = *(const float4*)(vp + r * DD);
      }
    }
    if (tile) __syncthreads();  // prior tile's frag reads complete

    // transpose-write current tile (waits only on ka/va, not kb/vb)
#pragma unroll
    for (int c = 0; c < 4; ++c) {
      *(unsigned int*)&Kt[dq * 4 + c][mr]     = pk2(fc(ka[0], c), fc(ka[1], c));
      *(unsigned int*)&Kt[dq * 4 + c][mr + 2] = pk2(fc(ka[2], c), fc(ka[3], c));
      *(unsigned int*)&Vt[dq * 4 + c][mr]     = pk2(fc(va[0], c), fc(va[1], c));
      *(unsigned int*)&Vt[dq * 4 + c][mr + 2] = pk2(fc(va[2], c), fc(va[3], c));
    }
    __syncthreads();

    short8 a0 = *(const short8*)&Vt[wave * 32 + lr][kg * 8];
    short8 a1 = *(const short8*)&Vt[wave * 32 + 16 + lr][kg * 8];
#pragma unroll
    for (int tc = 0; tc < 8; ++tc) {
      short8 b = *(const short8*)&Kt[tc * 16 + lr][kg * 8];
      acc[0][tc] = __builtin_amdgcn_mfma_f32_16x16x32_bf16(a0, b, acc[0][tc], 0, 0, 0);
      acc[1][tc] = __builtin_amdgcn_mfma_f32_16x16x32_bf16(a1, b, acc[1][tc], 0, 0, 0);
    }
    if (tile < 3) {
#pragma unroll
      for (int r = 0; r < 4; ++r) { ka[r] = kb[r]; va[r] = vb[r]; }
    }
  }

  if (PARTIAL) {
    float* Pp = P + (size_t)blockIdx.x * (DD * DD);
#pragma unroll
    for (int tr = 0; tr < 2; ++tr)
#pragma unroll
      for (int tc = 0; tc < 8; ++tc)
#pragma unroll
        for (int r = 0; r < 4; ++r) {
          int i = wave * 32 + tr * 16 + kg * 4 + r;
          int j = tc * 16 + lr;
          Pp[i * DD + j] = acc[tr][tc][r];
        }
  } else {
    float* Wh = P + (size_t)bh * DD * DD;
#pragma unroll
    for (int tr = 0; tr < 2; ++tr)
#pragma unroll
      for (int tc = 0; tc < 8; ++tc)
#pragma unroll
        for (int r = 0; r < 4; ++r) {
          int i = wave * 32 + tr * 16 + kg * 4 + r;
          int j = tc * 16 + lr;
          __hip_atomic_fetch_add(&Wh[i * DD + j], acc[tr][tc][r],
                                 __ATOMIC_RELAXED, __HIP_MEMORY_SCOPE_AGENT);
        }
  }
}

// ---------------------------------------------------------------------------
// Reduce: Wb[bh][i] (bf16) = sum_{c=0..15} P[bh*16+c][i].  grid 512 x 256.
// ---------------------------------------------------------------------------
__global__ __launch_bounds__(256) void reduce_kernel(const float* __restrict__ P,
                                                     unsigned short* __restrict__ Wb) {
#pragma unroll
  for (int j = 0; j < 4; ++j) {
    int o = blockIdx.x * 1024 + j * 256 + threadIdx.x;
    int bh = o >> 14;
    int i = o & 16383;
    const float* p = P + ((size_t)bh << 18) + i;
    float s = 0.0f;
#pragma unroll
    for (int c = 0; c < 16; ++c) s += p[(size_t)c << 14];
    Wb[o] = f2bf(s);
  }
}

// fallback: fp32 W -> bf16
__global__ __launch_bounds__(256) void cvt_kernel(const float* __restrict__ Wf,
                                                  unsigned short* __restrict__ Wb) {
#pragma unroll
  for (int j = 0; j < 4; ++j) {
    int o = blockIdx.x * 1024 + j * 256 + threadIdx.x;
    Wb[o] = f2bf(Wf[o]);
  }
}

// ---------------------------------------------------------------------------
// Kernel 2: O[bh][l][d2] = SCALE * sum_d1 Q[bh][l][d1] * W[bh][d2][d1]
// grid = 32 heads * 32 row-blocks (64 rows), block = 256 (4 waves x 16 rows).
// Q issued before W staging so Q's HBM latency hides under W's L2 reads.
// ---------------------------------------------------------------------------
__global__ __launch_bounds__(256) void qw_kernel(const float* __restrict__ Qg,
                                                 const unsigned short* __restrict__ Wb,
                                                 float* __restrict__ Og) {
  const int bh = blockIdx.x >> 5;
  const int rblk = blockIdx.x & 31;
  const int t = threadIdx.x;
  const int wave = t >> 6;
  const int lane = t & 63;
  const int lr = lane & 15;
  const int kg = lane >> 4;

  __shared__ unsigned short Ws[128][136];  // [d2][d1] bf16, pad 8

  // 1) issue all Q loads (8 float4/thread)
  const float* Qb = Qg + ((size_t)bh * LL + rblk * 64 + wave * 16 + lr) * DD;
  float4 q[4][2];
#pragma unroll
  for (int ks = 0; ks < 4; ++ks)
#pragma unroll
    for (int j = 0; j < 2; ++j)
      q[ks][j] = *(const float4*)(Qb + ks * 32 + kg * 8 + j * 4);

  // 2) stage W (bf16, 32KB = 8 uint4/thread)
  const uint4* Wg = (const uint4*)(Wb + (size_t)bh * (DD * DD));
  uint4 wld[8];
#pragma unroll
  for (int it = 0; it < 8; ++it) wld[it] = Wg[t + it * 256];
#pragma unroll
  for (int it = 0; it < 8; ++it) {
    int g = t + it * 256;       // uint4 index; 16 per 128-short row
    int row = g >> 4;
    int c8 = (g & 15) * 8;
    *(uint4*)&Ws[row][c8] = wld[it];
  }
  __syncthreads();

  f32x4 acc[8];
#pragma unroll
  for (int b = 0; b < 8; ++b) acc[b] = (f32x4)(0.0f);

#pragma unroll
  for (int ks = 0; ks < 4; ++ks) {
    short8 bfr[8];
#pragma unroll
    for (int tc = 0; tc < 8; ++tc)
      bfr[tc] = *(const short8*)&Ws[tc * 16 + lr][ks * 32 + kg * 8];
    short8 af;
#pragma unroll
    for (int j = 0; j < 2; ++j) {
      af[j * 4 + 0] = (short)f2bf(q[ks][j].x);
      af[j * 4 + 1] = (short)f2bf(q[ks][j].y);
      af[j * 4 + 2] = (short)f2bf(q[ks][j].z);
      af[j * 4 + 3] = (short)f2bf(q[ks][j].w);
    }
#pragma unroll
    for (int tc = 0; tc < 8; ++tc)
      acc[tc] = __builtin_amdgcn_mfma_f32_16x16x32_bf16(af, bfr[tc], acc[tc], 0, 0, 0);
  }

  float* Ob = Og + ((size_t)bh * LL + rblk * 64 + wave * 16) * DD;
#pragma unroll
  for (int tc = 0; tc < 8; ++tc)
#pragma unroll
    for (int r = 0; r < 4; ++r)
      Ob[(kg * 4 + r) * DD + tc * 16 + lr] = acc[tc][r] * SCALE;
}

extern "C" void kernel_launch(void* const* d_in, const int* in_sizes, int n_in,
                              void* d_out, int out_size, void* d_ws, size_t ws_size,
                              hipStream_t stream) {
  const float* Q = (const float*)d_in[0];
  const float* K = (const float*)d_in[1];
  const float* V = (const float*)d_in[2];
  float* O = (float*)d_out;

  const size_t P_BYTES = (size_t)512 * DD * DD * sizeof(float);  // 32 MB partials
  const size_t W_BYTES = (size_t)NH * DD * DD * sizeof(unsigned short);  // 1 MB bf16

  if (ws_size >= P_BYTES + W_BYTES) {
    float* P = (float*)d_ws;
    unsigned short* Wb = (unsigned short*)((char*)d_ws + P_BYTES);
    ktv_kernel<true><<<dim3(512), dim3(256), 0, stream>>>(K, V, P);
    reduce_kernel<<<dim3(512), dim3(256), 0, stream>>>(P, Wb);
    qw_kernel<<<dim3(1024), dim3(256), 0, stream>>>(Q, Wb, O);
  } else {
    // fallback: HW fp32 atomics (no CAS loop) into 2MB W, then convert to bf16
    float* Wf = (float*)d_ws;
    unsigned short* Wb = (unsigned short*)((char*)d_ws + (size_t)NH * DD * DD * 4);
    hipMemsetAsync(d_ws, 0, (size_t)NH * DD * DD * sizeof(float), stream);
    ktv_kernel<false><<<dim3(512), dim3(256), 0, stream>>>(K, V, Wf);
    cvt_kernel<<<dim3(512), dim3(256), 0, stream>>>(Wf, Wb);
    qw_kernel<<<dim3(1024), dim3(256), 0, stream>>>(Q, Wb, O);
  }
}

// Round 4
// 143.930 us; speedup vs baseline: 1.1909x; 1.0282x over previous
//
#include <hip/hip_runtime.h>
#include <hip/hip_bf16.h>

typedef __attribute__((ext_vector_type(8))) short short8;
typedef __attribute__((ext_vector_type(4))) float f32x4;

#define LL 2048
#define DD 128
#define NH 32                      // B*H heads
#define SCALE 0.08838834764831845f // 1/sqrt(128)

__device__ __forceinline__ unsigned short f2bf(float f) {
  unsigned int u = __float_as_uint(f);
  u = u + 0x7FFFu + ((u >> 16) & 1u);  // RNE; inputs finite
  return (unsigned short)(u >> 16);
}
__device__ __forceinline__ unsigned int pk2(float a, float b) {
  return (unsigned int)f2bf(a) | ((unsigned int)f2bf(b) << 16);
}
__device__ __forceinline__ float fc(const float4& v, int c) {
  return ((const float*)&v)[c];
}

// ---------------------------------------------------------------------------
// Kernel 1: per-chunk partial W_p[d2][d1] = sum_{m in chunk} V[m][d2]*K[m][d1]
// grid = 32 heads * 16 chunks (128 m-rows each), block = 512 (8 waves).
// 2 blocks/CU -> 16 waves/CU. Register double-buffer across the 4 m-tiles.
// Wave w computes W rows [w*16, w*16+16) x all 128 cols (8 MFMA frags).
// ---------------------------------------------------------------------------
template <bool PARTIAL>
__global__ __launch_bounds__(512, 4) void ktv_kernel(const float* __restrict__ Kg,
                                                     const float* __restrict__ Vg,
                                                     float* __restrict__ P) {
  const int bh = blockIdx.x >> 4;
  const int chunk = blockIdx.x & 15;
  const int t = threadIdx.x;

  __shared__ unsigned short Kt[128][40];  // [d][m-tile(32)], 80B rows
  __shared__ unsigned short Vt[128][40];

  const int wave = t >> 6;
  const int lane = t & 63;
  const int lr = lane & 15;
  const int kg = lane >> 4;

  f32x4 acc[8];
#pragma unroll
  for (int b = 0; b < 8; ++b) acc[b] = (f32x4)(0.0f);

  const int dq = t >> 4;        // 0..31 : d-quad
  const int mr = (t & 15) << 1; // 0..30 : m-row base (2 rows/thread)
  const size_t hb = (size_t)bh * LL * DD;
  const float* kbase = Kg + hb + (size_t)(chunk * 128 + mr) * DD + dq * 4;
  const float* vbase = Vg + hb + (size_t)(chunk * 128 + mr) * DD + dq * 4;

  float4 k0a, k1a, v0a, v1a, k0b, k1b, v0b, v1b;
  k0a = *(const float4*)(kbase);
  k1a = *(const float4*)(kbase + DD);
  v0a = *(const float4*)(vbase);
  v1a = *(const float4*)(vbase + DD);

#pragma unroll
  for (int tile = 0; tile < 4; ++tile) {
    if (tile < 3) {  // prefetch next 32-row tile into regs
      const float* kp = kbase + (size_t)(tile + 1) * 32 * DD;
      const float* vp = vbase + (size_t)(tile + 1) * 32 * DD;
      k0b = *(const float4*)(kp);
      k1b = *(const float4*)(kp + DD);
      v0b = *(const float4*)(vp);
      v1b = *(const float4*)(vp + DD);
    }
    if (tile) __syncthreads();  // prior tile's frag reads complete

#pragma unroll
    for (int c = 0; c < 4; ++c) {
      *(unsigned int*)&Kt[dq * 4 + c][mr] = pk2(fc(k0a, c), fc(k1a, c));
      *(unsigned int*)&Vt[dq * 4 + c][mr] = pk2(fc(v0a, c), fc(v1a, c));
    }
    __syncthreads();

    short8 a0 = *(const short8*)&Vt[wave * 16 + lr][kg * 8];
#pragma unroll
    for (int tc = 0; tc < 8; ++tc) {
      short8 b = *(const short8*)&Kt[tc * 16 + lr][kg * 8];
      acc[tc] = __builtin_amdgcn_mfma_f32_16x16x32_bf16(a0, b, acc[tc], 0, 0, 0);
    }
    if (tile < 3) {
      k0a = k0b; k1a = k1b; v0a = v0b; v1a = v1b;
    }
  }

  if (PARTIAL) {
    float* Pp = P + (size_t)blockIdx.x * (DD * DD);
#pragma unroll
    for (int tc = 0; tc < 8; ++tc)
#pragma unroll
      for (int r = 0; r < 4; ++r) {
        int i = wave * 16 + kg * 4 + r;
        int j = tc * 16 + lr;
        Pp[i * DD + j] = acc[tc][r];
      }
  } else {
    float* Wh = P + (size_t)bh * DD * DD;
#pragma unroll
    for (int tc = 0; tc < 8; ++tc)
#pragma unroll
      for (int r = 0; r < 4; ++r) {
        int i = wave * 16 + kg * 4 + r;
        int j = tc * 16 + lr;
        __hip_atomic_fetch_add(&Wh[i * DD + j], acc[tc][r],
                               __ATOMIC_RELAXED, __HIP_MEMORY_SCOPE_AGENT);
      }
  }
}

// ---------------------------------------------------------------------------
// Reduce: Wb[bh] (bf16, pre-scaled) = SCALE * sum_{c=0..15} P[bh*16+c].
// 131072 tasks of float4; grid 512 x 256, 1 task/thread, coalesced.
// ---------------------------------------------------------------------------
__global__ __launch_bounds__(256) void reduce_kernel(const float* __restrict__ P,
                                                     unsigned short* __restrict__ Wb) {
  const int task = blockIdx.x * 256 + threadIdx.x;  // bh*4096 + i4
  const int bh = task >> 12;
  const int i4 = task & 4095;
  const float4* p = (const float4*)P + (((size_t)bh << 4) << 12) + i4;
  float4 s = make_float4(0.f, 0.f, 0.f, 0.f);
#pragma unroll
  for (int c = 0; c < 16; ++c) {
    float4 x = p[(size_t)c << 12];
    s.x += x.x; s.y += x.y; s.z += x.z; s.w += x.w;
  }
  uint2 o;
  o.x = pk2(s.x * SCALE, s.y * SCALE);
  o.y = pk2(s.z * SCALE, s.w * SCALE);
  ((uint2*)Wb)[task] = o;
}

// fallback: fp32 W -> bf16 (pre-scaled)
__global__ __launch_bounds__(256) void cvt_kernel(const float* __restrict__ Wf,
                                                  unsigned short* __restrict__ Wb) {
#pragma unroll
  for (int j = 0; j < 4; ++j) {
    int o = blockIdx.x * 1024 + j * 256 + threadIdx.x;
    Wb[o] = f2bf(Wf[o] * SCALE);
  }
}

// ---------------------------------------------------------------------------
// Kernel 2: O[bh][l][d2] = sum_d1 Q[bh][l][d1] * Wb[bh][d2][d1]  (Wb pre-scaled)
// grid = 32 heads * 16 row-blocks (128 rows), block = 512 (8 waves x 16 rows).
// Q issued before W staging; q->bf16 converted early to cut VGPR live range.
// ---------------------------------------------------------------------------
__global__ __launch_bounds__(512, 4) void qw_kernel(const float* __restrict__ Qg,
                                                    const unsigned short* __restrict__ Wb,
                                                    float* __restrict__ Og) {
  const int bh = blockIdx.x >> 4;
  const int rblk = blockIdx.x & 15;
  const int t = threadIdx.x;
  const int wave = t >> 6;
  const int lane = t & 63;
  const int lr = lane & 15;
  const int kg = lane >> 4;

  __shared__ unsigned short Ws[128][136];  // [d2][d1] bf16, pad 8

  // 1) issue all Q loads (8 float4/thread; lane's 32B contiguous per ks)
  const float* Qb = Qg + ((size_t)bh * LL + rblk * 128 + wave * 16 + lr) * DD;
  float4 q[4][2];
#pragma unroll
  for (int ks = 0; ks < 4; ++ks)
#pragma unroll
    for (int j = 0; j < 2; ++j)
      q[ks][j] = *(const float4*)(Qb + ks * 32 + kg * 8 + j * 4);

  // 2) stage W (bf16, 32KB = 4 uint4/thread)
  const uint4* Wg = (const uint4*)(Wb + (size_t)bh * (DD * DD));
  uint4 wld[4];
#pragma unroll
  for (int it = 0; it < 4; ++it) wld[it] = Wg[t + it * 512];
#pragma unroll
  for (int it = 0; it < 4; ++it) {
    int g = t + it * 512;  // uint4 index; 16 per 128-short row
    int row = g >> 4;
    int c8 = (g & 15) * 8;
    *(uint4*)&Ws[row][c8] = wld[it];
  }

  // 3) convert q to bf16 fragments while W staging lands
  short8 abf[4];
#pragma unroll
  for (int ks = 0; ks < 4; ++ks)
#pragma unroll
    for (int j = 0; j < 2; ++j) {
      abf[ks][j * 4 + 0] = (short)f2bf(q[ks][j].x);
      abf[ks][j * 4 + 1] = (short)f2bf(q[ks][j].y);
      abf[ks][j * 4 + 2] = (short)f2bf(q[ks][j].z);
      abf[ks][j * 4 + 3] = (short)f2bf(q[ks][j].w);
    }
  __syncthreads();

  f32x4 acc[8];
#pragma unroll
  for (int b = 0; b < 8; ++b) acc[b] = (f32x4)(0.0f);

#pragma unroll
  for (int ks = 0; ks < 4; ++ks) {
#pragma unroll
    for (int tc = 0; tc < 8; ++tc) {
      short8 bfr = *(const short8*)&Ws[tc * 16 + lr][ks * 32 + kg * 8];
      acc[tc] = __builtin_amdgcn_mfma_f32_16x16x32_bf16(abf[ks], bfr, acc[tc], 0, 0, 0);
    }
  }

  float* Ob = Og + ((size_t)bh * LL + rblk * 128 + wave * 16) * DD;
#pragma unroll
  for (int tc = 0; tc < 8; ++tc)
#pragma unroll
    for (int r = 0; r < 4; ++r)
      Ob[(kg * 4 + r) * DD + tc * 16 + lr] = acc[tc][r];
}

extern "C" void kernel_launch(void* const* d_in, const int* in_sizes, int n_in,
                              void* d_out, int out_size, void* d_ws, size_t ws_size,
                              hipStream_t stream) {
  const float* Q = (const float*)d_in[0];
  const float* K = (const float*)d_in[1];
  const float* V = (const float*)d_in[2];
  float* O = (float*)d_out;

  const size_t P_BYTES = (size_t)512 * DD * DD * sizeof(float);             // 32 MB
  const size_t W_BYTES = (size_t)NH * DD * DD * sizeof(unsigned short);     // 1 MB

  if (ws_size >= P_BYTES + W_BYTES) {
    float* P = (float*)d_ws;
    unsigned short* Wb = (unsigned short*)((char*)d_ws + P_BYTES);
    ktv_kernel<true><<<dim3(512), dim3(512), 0, stream>>>(K, V, P);
    reduce_kernel<<<dim3(512), dim3(256), 0, stream>>>(P, Wb);
    qw_kernel<<<dim3(512), dim3(512), 0, stream>>>(Q, Wb, O);
  } else {
    // fallback: HW fp32 atomics into 2MB W, then convert+scale to bf16
    float* Wf = (float*)d_ws;
    unsigned short* Wb = (unsigned short*)((char*)d_ws + (size_t)NH * DD * DD * 4);
    hipMemsetAsync(d_ws, 0, (size_t)NH * DD * DD * sizeof(float), stream);
    ktv_kernel<false><<<dim3(512), dim3(512), 0, stream>>>(K, V, Wf);
    cvt_kernel<<<dim3(512), dim3(256), 0, stream>>>(Wf, Wb);
    qw_kernel<<<dim3(512), dim3(512), 0, stream>>>(Q, Wb, O);
  }
}